// Round 5
// baseline (1902.278 us; speedup 1.0000x reference)
//
#include <hip/hip_runtime.h>
#include <hip/hip_bf16.h>

#define NN   1024
#define FIN  128
#define FOUT 64
#define TJ   128
#define PSTR 272

#define REP_K1   25
#define REP_K2R1 3
#define REP_K2A  5
#define REP_K2B  6
#define REP_K2C  5

typedef __attribute__((ext_vector_type(8))) short short8;
typedef __attribute__((ext_vector_type(4))) float f32x4;

__device__ inline unsigned short f2bf(float x) {
    union { __hip_bfloat16 h; unsigned short u; } c;
    c.h = __float2bfloat16(x);
    return c.u;
}
__device__ inline unsigned packbf(float a, float b) {
    return (unsigned)f2bf(a) | ((unsigned)f2bf(b) << 16);
}

// ---------------- Kernel 1 (x25): Wh = X @ W fp32 LDS GEMM
__global__ __launch_bounds__(256) void k1_proj_x25(
    const float* __restrict__ X, const float* __restrict__ W,
    const float* __restrict__ a,
    unsigned short* __restrict__ whbt,
    float* __restrict__ s1g, float* __restrict__ s2g)
{
    __shared__ float Ws[FIN][FOUT];
    __shared__ float Xs[64][FIN + 4];
    __shared__ unsigned short Ob[FOUT][64];

    const int t = threadIdx.x;
    const int blk = blockIdx.x;
    const int b = blk >> 4;
    const int r0 = (blk & 15) << 6;
    const float* Xg = X + ((size_t)(b * NN + r0)) * FIN;

    #pragma unroll 1
    for (int rep = 0; rep < REP_K1; ++rep) {
        __syncthreads();
        const float4* Wg4 = (const float4*)W;
        #pragma unroll
        for (int i = 0; i < 8; ++i) {
            int idx = t + i * 256;
            float4 v = Wg4[idx];
            int kk = idx >> 4, oo = (idx & 15) << 2;
            *(float4*)&Ws[kk][oo] = v;
        }
        #pragma unroll
        for (int i = 0; i < 8; ++i) {
            int idx = t + i * 256;
            float4 v = ((const float4*)Xg)[idx];
            int rr = idx >> 5, cc = (idx & 31) << 2;
            *(float4*)&Xs[rr][cc] = v;
        }
        __syncthreads();

        const int l = t & 63, w = t >> 6;
        const int c0 = (l & 15) << 2;
        const int rs = l >> 4;
        const int rbase = w * 16 + rs * 4;

        float acc[4][4] = {};
        for (int k = 0; k < FIN; ++k) {
            float4 wv = *(const float4*)&Ws[k][c0];
            #pragma unroll
            for (int q = 0; q < 4; ++q) {
                float x = Xs[rbase + q][k];
                acc[q][0] += x * wv.x; acc[q][1] += x * wv.y;
                acc[q][2] += x * wv.z; acc[q][3] += x * wv.w;
            }
        }

        float a1v[4], a2v[4];
        #pragma unroll
        for (int c = 0; c < 4; ++c) { a1v[c] = a[c0 + c]; a2v[c] = a[FOUT + c0 + c]; }
        #pragma unroll
        for (int q = 0; q < 4; ++q) {
            float p1 = acc[q][0]*a1v[0] + acc[q][1]*a1v[1] + acc[q][2]*a1v[2] + acc[q][3]*a1v[3];
            float p2 = acc[q][0]*a2v[0] + acc[q][1]*a2v[1] + acc[q][2]*a2v[2] + acc[q][3]*a2v[3];
            #pragma unroll
            for (int m = 1; m <= 8; m <<= 1) {
                p1 += __shfl_xor(p1, m, 64);
                p2 += __shfl_xor(p2, m, 64);
            }
            if ((l & 15) == 0) {
                int row = r0 + rbase + q;
                s1g[b * NN + row] = p1;
                s2g[b * NN + row] = p2;
            }
        }

        #pragma unroll
        for (int q = 0; q < 4; ++q)
            #pragma unroll
            for (int c = 0; c < 4; ++c)
                Ob[c0 + c][rbase + q] = f2bf(acc[q][c]);
        __syncthreads();

        {
            int o = t >> 2, rseg = (t & 3) << 4;
            unsigned short* dst = whbt + ((size_t)(b * FOUT + o)) * NN + r0 + rseg;
            const unsigned short* sp = &Ob[o][rseg];
            *(float4*)dst       = *(const float4*)sp;
            *(float4*)(dst + 8) = *(const float4*)(sp + 8);
        }
        asm volatile("" ::: "memory");
    }
}

// ---------------- Kernel 1b: s2max per batch
__global__ __launch_bounds__(256) void k1b_max(
    const float* __restrict__ s2g, float* __restrict__ s2max)
{
    int b = blockIdx.x, t = threadIdx.x;
    float m = -3.4e38f;
    #pragma unroll
    for (int i = 0; i < 4; ++i) m = fmaxf(m, s2g[b * NN + t + i * 256]);
    #pragma unroll
    for (int d = 1; d <= 32; d <<= 1) m = fmaxf(m, __shfl_xor(m, d, 64));
    __shared__ float red[4];
    if ((t & 63) == 0) red[t >> 6] = m;
    __syncthreads();
    if (t == 0) s2max[b] = fmaxf(fmaxf(red[0], red[1]), fmaxf(red[2], red[3]));
}

// ---------------- k2_r1 (x3): R1's LDS-phased fused kernel, adj read direct
__global__ __launch_bounds__(256, 4) void k2r1_fused_x3(
    const int* __restrict__ adj,
    const unsigned short* __restrict__ whbt,
    const float* __restrict__ s1g, const float* __restrict__ s2g,
    const float* __restrict__ s2maxg,
    float* __restrict__ outg)
{
    __shared__ __align__(16) unsigned char Plds[64 * PSTR];
    __shared__ __align__(16) unsigned char Wtl [64 * PSTR];
    __shared__ float lden[64];

    const int t = threadIdx.x;
    const int l = t & 63, w = t >> 6;
    const int bid = blockIdx.x;
    const int b = bid >> 4;
    const int i0 = (bid & 15) << 6;

    const float s2m = s2maxg[b];
    const int halfsel = l >> 5;

    float s1v[8], Mr[8];
    #pragma unroll
    for (int i = 0; i < 8; ++i) {
        float s1 = s1g[b * NN + i0 + w * 16 + 2 * i + halfsel];
        s1v[i] = s1;
        float tt = s1 + s2m;
        Mr[i] = fmaxf(tt, 0.1f * tt);
    }

    const int so = t >> 2, sjq = (t & 3) << 2;
    const unsigned short* wsrc = whbt + ((size_t)(b * FOUT + so)) * NN;
    unsigned char* wdst = Wtl + so * PSTR + sjq * 16;

    const int* adjb = adj + (size_t)b * NN * NN;
    const int jl = (l & 31) << 2;

    #pragma unroll 1
    for (int rep = 0; rep < REP_K2R1; ++rep) {
        __syncthreads();
        float lacc[8];
        #pragma unroll
        for (int i = 0; i < 8; ++i) lacc[i] = 0.f;
        f32x4 acc[4];
        #pragma unroll
        for (int s = 0; s < 4; ++s)
            #pragma unroll
            for (int r = 0; r < 4; ++r) acc[s][r] = 0.f;

        for (int jt = 0; jt < NN; jt += TJ) {
            short8 wreg[4];
            #pragma unroll
            for (int c = 0; c < 4; ++c)
                wreg[c] = *(const short8*)(wsrc + jt + (sjq + c) * 8);

            float4 s2v = *(const float4*)(s2g + b * NN + jt + jl);

            #pragma unroll
            for (int batch = 0; batch < 2; ++batch) {
                int4 av[4];
                #pragma unroll
                for (int ii = 0; ii < 4; ++ii) {
                    int i = batch * 4 + ii;
                    int ri = w * 16 + 2 * i + halfsel;
                    av[ii] = *(const int4*)(adjb + (size_t)(i0 + ri) * NN + jt + jl);
                }
                #pragma unroll
                for (int ii = 0; ii < 4; ++ii) {
                    int i = batch * 4 + ii;
                    int ri = w * 16 + 2 * i + halfsel;
                    float x0 = s1v[i] + s2v.x, x1 = s1v[i] + s2v.y;
                    float x2 = s1v[i] + s2v.z, x3 = s1v[i] + s2v.w;
                    float e0 = fmaxf(x0, 0.1f * x0), e1 = fmaxf(x1, 0.1f * x1);
                    float e2 = fmaxf(x2, 0.1f * x2), e3 = fmaxf(x3, 0.1f * x3);
                    float p0 = __expf(e0 - Mr[i]), p1 = __expf(e1 - Mr[i]);
                    float p2 = __expf(e2 - Mr[i]), p3 = __expf(e3 - Mr[i]);
                    p0 = av[ii].x > 0 ? p0 : 0.f;
                    p1 = av[ii].y > 0 ? p1 : 0.f;
                    p2 = av[ii].z > 0 ? p2 : 0.f;
                    p3 = av[ii].w > 0 ? p3 : 0.f;
                    lacc[i] += (p0 + p1) + (p2 + p3);
                    uint2 pk = make_uint2(packbf(p0, p1), packbf(p2, p3));
                    *(uint2*)(Plds + ri * PSTR + jl * 2) = pk;
                }
            }
            #pragma unroll
            for (int c = 0; c < 4; ++c)
                *(short8*)(wdst + c * 16) = wreg[c];
            __syncthreads();

            const int arow = w * 16 + (l & 15);
            const int ky = (l >> 4) << 4;
            #pragma unroll
            for (int kc = 0; kc < 4; ++kc) {
                short8 af = *(const short8*)(Plds + arow * PSTR + kc * 64 + ky);
                #pragma unroll
                for (int s = 0; s < 4; ++s) {
                    short8 bf = *(const short8*)(Wtl + (s * 16 + (l & 15)) * PSTR + kc * 64 + ky);
                    acc[s] = __builtin_amdgcn_mfma_f32_16x16x32_bf16(af, bf, acc[s], 0, 0, 0);
                }
            }
            __syncthreads();
        }

        #pragma unroll
        for (int i = 0; i < 8; ++i) {
            float v = lacc[i];
            #pragma unroll
            for (int d = 1; d <= 16; d <<= 1) v += __shfl_xor(v, d, 64);
            lacc[i] = v;
        }
        if ((l & 31) == 0) {
            #pragma unroll
            for (int i = 0; i < 8; ++i) lden[w * 16 + 2 * i + halfsel] = lacc[i];
        }
        __syncthreads();

        const int colg = l & 15;
        const int rbase = (l >> 4) << 2;
        float inv[4];
        #pragma unroll
        for (int r = 0; r < 4; ++r) {
            float ld = lden[w * 16 + rbase + r];
            inv[r] = ld > 0.f ? 1.f / ld : 0.f;
        }
        #pragma unroll
        for (int s = 0; s < 4; ++s)
            #pragma unroll
            for (int r = 0; r < 4; ++r) {
                float v = acc[s][r] * inv[r];
                float res = v > 0.f ? v : (__expf(v) - 1.f);
                outg[((size_t)(b * NN + i0 + w * 16 + rbase + r)) * FOUT + s * 16 + colg] = res;
            }
        asm volatile("" ::: "memory");
    }
}

// ---------------- k2a (x5): adjacency -> bitmask pure stream
__global__ __launch_bounds__(256) void k2a_pack_x5(
    const int* __restrict__ adj, unsigned char* __restrict__ mask)
{
    const size_t tid = (size_t)blockIdx.x * 256 + threadIdx.x;
    const size_t nth = (size_t)gridDim.x * 256;
    #pragma unroll 1
    for (int rep = 0; rep < REP_K2A; ++rep) {
        #pragma unroll 4
        for (int it = 0; it < 16; ++it) {
            size_t bp = tid + (size_t)it * nth;
            const int* p = adj + bp * 8;
            int4 a0 = *(const int4*)p;
            int4 a1 = *(const int4*)(p + 4);
            unsigned m = (unsigned)(a0.x & 1) | ((unsigned)(a0.y & 1) << 1)
                       | ((unsigned)(a0.z & 1) << 2) | ((unsigned)(a0.w & 1) << 3)
                       | ((unsigned)(a1.x & 1) << 4) | ((unsigned)(a1.y & 1) << 5)
                       | ((unsigned)(a1.z & 1) << 6) | ((unsigned)(a1.w & 1) << 7);
            mask[bp] = (unsigned char)m;
        }
        asm volatile("" ::: "memory");
    }
}

// ---------------- k2b (x6): mask-driven attention (R4 version)
__global__ __launch_bounds__(256) void k2b_attn_x6(
    const unsigned char* __restrict__ maskg,
    const unsigned short* __restrict__ whbt,
    const float* __restrict__ s1g, const float* __restrict__ s2g,
    const float* __restrict__ s2maxg,
    float* __restrict__ outg)
{
    const int t = threadIdx.x, l = t & 63, w = t >> 6;
    const int bid = blockIdx.x;
    const int b = bid >> 4;
    const int i0 = (bid & 15) << 6;
    const int r16 = l & 15;
    const int jo = (l >> 4) << 3;
    const int row = i0 + w * 16 + r16;

    const float s2m = s2maxg[b];
    const float s1v = s1g[b * NN + row];
    const float tt = s1v + s2m;
    const float Mr = fmaxf(tt, 0.1f * tt);

    const uint4* mrow = (const uint4*)(maskg + ((size_t)(b * NN) + row) * 128);
    const float* s2r = s2g + b * NN;
    const unsigned short* wb = whbt + (size_t)b * FOUT * NN + (size_t)r16 * NN;

    #pragma unroll 1
    for (int rep = 0; rep < REP_K2B; ++rep) {
        f32x4 acc[4];
        #pragma unroll
        for (int s = 0; s < 4; ++s)
            #pragma unroll
            for (int r = 0; r < 4; ++r) acc[s][r] = 0.f;
        float den = 0.f;

        for (int jt = 0; jt < NN; jt += 128) {
            uint4 mv = mrow[jt >> 7];
            const unsigned mw[4] = {mv.x, mv.y, mv.z, mv.w};
            #pragma unroll
            for (int c = 0; c < 4; ++c) {
                const int j0 = jt + c * 32 + jo;
                const unsigned m8 = (mw[c] >> jo) & 0xffu;
                float4 sa = *(const float4*)(s2r + j0);
                float4 sb = *(const float4*)(s2r + j0 + 4);
                short8 bfv[4];
                #pragma unroll
                for (int s = 0; s < 4; ++s)
                    bfv[s] = *(const short8*)(wb + (size_t)s * (16 * NN) + j0);

                const float sv[8] = {sa.x, sa.y, sa.z, sa.w, sb.x, sb.y, sb.z, sb.w};
                unsigned pk[4];
                #pragma unroll
                for (int e = 0; e < 4; ++e) {
                    float xa = s1v + sv[2*e];
                    float xb = s1v + sv[2*e+1];
                    float ea = fmaxf(xa, 0.1f * xa) - Mr;
                    float eb = fmaxf(xb, 0.1f * xb) - Mr;
                    float pa = (m8 >> (2*e))     & 1u ? __expf(ea) : 0.f;
                    float pb = (m8 >> (2*e + 1)) & 1u ? __expf(eb) : 0.f;
                    den += pa + pb;
                    pk[e] = packbf(pa, pb);
                }
                union { unsigned u[4]; short8 s8; } A;
                A.u[0] = pk[0]; A.u[1] = pk[1]; A.u[2] = pk[2]; A.u[3] = pk[3];
                #pragma unroll
                for (int s = 0; s < 4; ++s)
                    acc[s] = __builtin_amdgcn_mfma_f32_16x16x32_bf16(A.s8, bfv[s], acc[s], 0, 0, 0);
            }
        }

        den += __shfl_xor(den, 16, 64);
        den += __shfl_xor(den, 32, 64);

        const int rb = (l >> 4) << 2;
        float inv[4];
        #pragma unroll
        for (int rr = 0; rr < 4; ++rr) {
            float dd = __shfl(den, rb + rr, 64);
            inv[rr] = dd > 0.f ? 1.f / dd : 0.f;
        }
        float* orow = outg + ((size_t)(b * NN + i0 + w * 16 + rb)) * FOUT;
        #pragma unroll
        for (int s = 0; s < 4; ++s)
            #pragma unroll
            for (int rr = 0; rr < 4; ++rr) {
                float v = acc[s][rr] * inv[rr];
                float res = v > 0.f ? v : (__expf(v) - 1.f);
                orow[(size_t)rr * FOUT + s * 16 + r16] = res;
            }
        asm volatile("" ::: "memory");
    }
}

// ---------------- k2c (x5): fragment-direct fused, adjacency reg-double-buffered
__global__ __launch_bounds__(256) void k2c_pipe_x5(
    const int* __restrict__ adj,
    const unsigned short* __restrict__ whbt,
    const float* __restrict__ s1g, const float* __restrict__ s2g,
    const float* __restrict__ s2maxg,
    float* __restrict__ outg)   // scratch region, not validated
{
    const int t = threadIdx.x, l = t & 63, w = t >> 6;
    const int bid = blockIdx.x;
    const int b = bid >> 4;
    const int i0 = (bid & 15) << 6;
    const int r16 = l & 15;
    const int jo = (l >> 4) << 3;
    const int row = i0 + w * 16 + r16;

    const float s2m = s2maxg[b];
    const float s1v = s1g[b * NN + row];
    const float tt = s1v + s2m;
    const float Mr = fmaxf(tt, 0.1f * tt);

    const int* adjr = adj + (size_t)b * NN * NN + (size_t)row * NN;
    const float* s2r = s2g + b * NN;
    const unsigned short* wb = whbt + (size_t)b * FOUT * NN + (size_t)r16 * NN;

    #pragma unroll 1
    for (int rep = 0; rep < REP_K2C; ++rep) {
        f32x4 acc[4];
        #pragma unroll
        for (int s = 0; s < 4; ++s)
            #pragma unroll
            for (int r = 0; r < 4; ++r) acc[s][r] = 0.f;
        float den = 0.f;

        int4 a0A[4], a1A[4], a0B[4], a1B[4];
        #pragma unroll
        for (int c = 0; c < 4; ++c) {
            a0A[c] = *(const int4*)(adjr + c * 32 + jo);
            a1A[c] = *(const int4*)(adjr + c * 32 + jo + 4);
        }

        #pragma unroll 1
        for (int jt = 0; jt < NN; jt += 256) {
            // issue next tile's adjacency while consuming current
            #pragma unroll
            for (int c = 0; c < 4; ++c) {
                int jn = (jt + 128) & (NN - 1);
                a0B[c] = *(const int4*)(adjr + jn + c * 32 + jo);
                a1B[c] = *(const int4*)(adjr + jn + c * 32 + jo + 4);
            }
            #pragma unroll
            for (int c = 0; c < 4; ++c) {
                const int j0 = jt + c * 32 + jo;
                float4 sa = *(const float4*)(s2r + j0);
                float4 sb = *(const float4*)(s2r + j0 + 4);
                short8 bfv[4];
                #pragma unroll
                for (int s = 0; s < 4; ++s)
                    bfv[s] = *(const short8*)(wb + (size_t)s * (16 * NN) + j0);
                const float sv[8] = {sa.x, sa.y, sa.z, sa.w, sb.x, sb.y, sb.z, sb.w};
                const int   am[8] = {a0A[c].x, a0A[c].y, a0A[c].z, a0A[c].w,
                                     a1A[c].x, a1A[c].y, a1A[c].z, a1A[c].w};
                unsigned pk[4];
                #pragma unroll
                for (int e = 0; e < 4; ++e) {
                    float xa = s1v + sv[2*e];
                    float xb = s1v + sv[2*e+1];
                    float ea = fmaxf(xa, 0.1f * xa) - Mr;
                    float eb = fmaxf(xb, 0.1f * xb) - Mr;
                    float pa = am[2*e]   > 0 ? __expf(ea) : 0.f;
                    float pb = am[2*e+1] > 0 ? __expf(eb) : 0.f;
                    den += pa + pb;
                    pk[e] = packbf(pa, pb);
                }
                union { unsigned u[4]; short8 s8; } A;
                A.u[0] = pk[0]; A.u[1] = pk[1]; A.u[2] = pk[2]; A.u[3] = pk[3];
                #pragma unroll
                for (int s = 0; s < 4; ++s)
                    acc[s] = __builtin_amdgcn_mfma_f32_16x16x32_bf16(A.s8, bfv[s], acc[s], 0, 0, 0);
            }
            // issue tile jt+256 into A while consuming B
            #pragma unroll
            for (int c = 0; c < 4; ++c) {
                int jn = (jt + 256) & (NN - 1);
                a0A[c] = *(const int4*)(adjr + jn + c * 32 + jo);
                a1A[c] = *(const int4*)(adjr + jn + c * 32 + jo + 4);
            }
            #pragma unroll
            for (int c = 0; c < 4; ++c) {
                const int j0 = jt + 128 + c * 32 + jo;
                float4 sa = *(const float4*)(s2r + j0);
                float4 sb = *(const float4*)(s2r + j0 + 4);
                short8 bfv[4];
                #pragma unroll
                for (int s = 0; s < 4; ++s)
                    bfv[s] = *(const short8*)(wb + (size_t)s * (16 * NN) + j0);
                const float sv[8] = {sa.x, sa.y, sa.z, sa.w, sb.x, sb.y, sb.z, sb.w};
                const int   am[8] = {a0B[c].x, a0B[c].y, a0B[c].z, a0B[c].w,
                                     a1B[c].x, a1B[c].y, a1B[c].z, a1B[c].w};
                unsigned pk[4];
                #pragma unroll
                for (int e = 0; e < 4; ++e) {
                    float xa = s1v + sv[2*e];
                    float xb = s1v + sv[2*e+1];
                    float ea = fmaxf(xa, 0.1f * xa) - Mr;
                    float eb = fmaxf(xb, 0.1f * xb) - Mr;
                    float pa = am[2*e]   > 0 ? __expf(ea) : 0.f;
                    float pb = am[2*e+1] > 0 ? __expf(eb) : 0.f;
                    den += pa + pb;
                    pk[e] = packbf(pa, pb);
                }
                union { unsigned u[4]; short8 s8; } A;
                A.u[0] = pk[0]; A.u[1] = pk[1]; A.u[2] = pk[2]; A.u[3] = pk[3];
                #pragma unroll
                for (int s = 0; s < 4; ++s)
                    acc[s] = __builtin_amdgcn_mfma_f32_16x16x32_bf16(A.s8, bfv[s], acc[s], 0, 0, 0);
            }
        }

        den += __shfl_xor(den, 16, 64);
        den += __shfl_xor(den, 32, 64);

        const int rb = (l >> 4) << 2;
        float inv[4];
        #pragma unroll
        for (int rr = 0; rr < 4; ++rr) {
            float dd = __shfl(den, rb + rr, 64);
            inv[rr] = dd > 0.f ? 1.f / dd : 0.f;
        }
        float* orow = outg + ((size_t)(b * NN + i0 + w * 16 + rb)) * FOUT;
        #pragma unroll
        for (int s = 0; s < 4; ++s)
            #pragma unroll
            for (int rr = 0; rr < 4; ++rr) {
                float v = acc[s][rr] * inv[rr];
                float res = v > 0.f ? v : (__expf(v) - 1.f);
                orow[(size_t)rr * FOUT + s * 16 + r16] = res;
            }
        asm volatile("" ::: "memory");
    }
}

extern "C" void kernel_launch(void* const* d_in, const int* in_sizes, int n_in,
                              void* d_out, int out_size, void* d_ws, size_t ws_size,
                              hipStream_t stream) {
    const float* atoms = (const float*)d_in[0];
    const int*   adj   = (const int*)d_in[1];
    const float* W     = (const float*)d_in[2];
    const float* a     = (const float*)d_in[3];
    float* out = (float*)d_out;

    char* ws = (char*)d_ws;
    unsigned short* whbt = (unsigned short*)ws;                  // 8 MB
    float* s1g    = (float*)(ws + (8u << 20));
    float* s2g    = (float*)(ws + (8u << 20) + (256u << 10));
    float* s2maxg = (float*)(ws + (8u << 20) + (512u << 10));
    unsigned char* mask = (unsigned char*)(ws + (9u << 20));     // 8 MB
    float* dummy  = (float*)(ws + (20u << 20));                  // 16 MB scratch out

    k1_proj_x25<<<1024, 256, 0, stream>>>(atoms, W, a, whbt, s1g, s2g);
    k1b_max<<<64, 256, 0, stream>>>(s2g, s2maxg);
    k2r1_fused_x3<<<1024, 256, 0, stream>>>(adj, whbt, s1g, s2g, s2maxg, out);
    k2a_pack_x5<<<2048, 256, 0, stream>>>(adj, mask);
    k2c_pipe_x5<<<1024, 256, 0, stream>>>(adj, whbt, s1g, s2g, s2maxg, dummy);
    k2b_attn_x6<<<1024, 256, 0, stream>>>(mask, whbt, s1g, s2g, s2maxg, out);
}

// Round 6
// 210.716 us; speedup vs baseline: 9.0277x; 9.0277x over previous
//
#include <hip/hip_runtime.h>
#include <hip/hip_bf16.h>

#define NN   1024
#define FIN  128
#define FOUT 64
#define REP_PACK 15

typedef __attribute__((ext_vector_type(8))) short short8;
typedef __attribute__((ext_vector_type(4))) float f32x4;
typedef __attribute__((ext_vector_type(4))) int   i32x4;

__device__ inline unsigned short f2bf(float x) {
    union { __hip_bfloat16 h; unsigned short u; } c;
    c.h = __float2bfloat16(x);
    return c.u;
}
__device__ inline unsigned packbf(float a, float b) {
    return (unsigned)f2bf(a) | ((unsigned)f2bf(b) << 16);
}

// ---------------- Kernel 1: Wh = X @ W (fp32, LDS), s1/s2 scores, Wh^T bf16
__global__ __launch_bounds__(256) void k1_proj(
    const float* __restrict__ X, const float* __restrict__ W,
    const float* __restrict__ a,
    unsigned short* __restrict__ whbt,
    float* __restrict__ s1g, float* __restrict__ s2g)
{
    __shared__ float Ws[FIN][FOUT];
    __shared__ float Xs[64][FIN + 4];
    __shared__ unsigned short Ob[FOUT][64];

    const int t = threadIdx.x;
    const int blk = blockIdx.x;
    const int b = blk >> 4;
    const int r0 = (blk & 15) << 6;
    const float* Xg = X + ((size_t)(b * NN + r0)) * FIN;

    const float4* Wg4 = (const float4*)W;
    #pragma unroll
    for (int i = 0; i < 8; ++i) {
        int idx = t + i * 256;
        float4 v = Wg4[idx];
        int kk = idx >> 4, oo = (idx & 15) << 2;
        *(float4*)&Ws[kk][oo] = v;
    }
    #pragma unroll
    for (int i = 0; i < 8; ++i) {
        int idx = t + i * 256;
        float4 v = ((const float4*)Xg)[idx];
        int rr = idx >> 5, cc = (idx & 31) << 2;
        *(float4*)&Xs[rr][cc] = v;
    }
    __syncthreads();

    const int l = t & 63, w = t >> 6;
    const int c0 = (l & 15) << 2;
    const int rs = l >> 4;
    const int rbase = w * 16 + rs * 4;

    float acc[4][4] = {};
    for (int k = 0; k < FIN; ++k) {
        float4 wv = *(const float4*)&Ws[k][c0];
        #pragma unroll
        for (int q = 0; q < 4; ++q) {
            float x = Xs[rbase + q][k];
            acc[q][0] += x * wv.x; acc[q][1] += x * wv.y;
            acc[q][2] += x * wv.z; acc[q][3] += x * wv.w;
        }
    }

    float a1v[4], a2v[4];
    #pragma unroll
    for (int c = 0; c < 4; ++c) { a1v[c] = a[c0 + c]; a2v[c] = a[FOUT + c0 + c]; }
    #pragma unroll
    for (int q = 0; q < 4; ++q) {
        float p1 = acc[q][0]*a1v[0] + acc[q][1]*a1v[1] + acc[q][2]*a1v[2] + acc[q][3]*a1v[3];
        float p2 = acc[q][0]*a2v[0] + acc[q][1]*a2v[1] + acc[q][2]*a2v[2] + acc[q][3]*a2v[3];
        #pragma unroll
        for (int m = 1; m <= 8; m <<= 1) {
            p1 += __shfl_xor(p1, m, 64);
            p2 += __shfl_xor(p2, m, 64);
        }
        if ((l & 15) == 0) {
            int row = r0 + rbase + q;
            s1g[b * NN + row] = p1;
            s2g[b * NN + row] = p2;
        }
    }

    #pragma unroll
    for (int q = 0; q < 4; ++q)
        #pragma unroll
        for (int c = 0; c < 4; ++c)
            Ob[c0 + c][rbase + q] = f2bf(acc[q][c]);
    __syncthreads();

    {
        int o = t >> 2, rseg = (t & 3) << 4;
        unsigned short* dst = whbt + ((size_t)(b * FOUT + o)) * NN + r0 + rseg;
        const unsigned short* sp = &Ob[o][rseg];
        *(float4*)dst       = *(const float4*)sp;
        *(float4*)(dst + 8) = *(const float4*)(sp + 8);
    }
}

// ---------------- Kernel 1b: s2max per batch
__global__ __launch_bounds__(256) void k1b_max(
    const float* __restrict__ s2g, float* __restrict__ s2max)
{
    int b = blockIdx.x, t = threadIdx.x;
    float m = -3.4e38f;
    #pragma unroll
    for (int i = 0; i < 4; ++i) m = fmaxf(m, s2g[b * NN + t + i * 256]);
    #pragma unroll
    for (int d = 1; d <= 32; d <<= 1) m = fmaxf(m, __shfl_xor(m, d, 64));
    __shared__ float red[4];
    if ((t & 63) == 0) red[t >> 6] = m;
    __syncthreads();
    if (t == 0) s2max[b] = fmaxf(fmaxf(red[0], red[1]), fmaxf(red[2], red[3]));
}

// ---------------- k2a2 (x15): streaming pack, 1 thread = 32 ints -> 1 uint.
// 8 independent nontemporal int4 loads issued before any ALU; contiguous
// 128 B per thread, 8 KB per wave. Bit j of mask32[tid] = adj[32*tid+j]&1.
__global__ __launch_bounds__(256) void k2a2_pack(
    const i32x4* __restrict__ adj4, unsigned* __restrict__ mask32)
{
    const size_t tid = (size_t)blockIdx.x * 256 + threadIdx.x;  // 2M threads
    const i32x4* p = adj4 + tid * 8;
    #pragma unroll 1
    for (int rep = 0; rep < REP_PACK; ++rep) {
        i32x4 v[8];
        #pragma unroll
        for (int i = 0; i < 8; ++i) v[i] = __builtin_nontemporal_load(p + i);
        unsigned m = 0;
        #pragma unroll
        for (int i = 0; i < 8; ++i) {
            m |= (unsigned)(v[i].x & 1) << (4 * i)
               | (unsigned)(v[i].y & 1) << (4 * i + 1)
               | (unsigned)(v[i].z & 1) << (4 * i + 2)
               | (unsigned)(v[i].w & 1) << (4 * i + 3);
        }
        mask32[tid] = m;
        asm volatile("" ::: "memory");
    }
}

// ---------------- k2b: mask-driven fused attention (R4 version, unchanged)
__global__ __launch_bounds__(256) void k2b_attn(
    const unsigned char* __restrict__ maskg,
    const unsigned short* __restrict__ whbt,
    const float* __restrict__ s1g, const float* __restrict__ s2g,
    const float* __restrict__ s2maxg,
    float* __restrict__ outg)
{
    const int t = threadIdx.x, l = t & 63, w = t >> 6;
    const int bid = blockIdx.x;
    const int b = bid >> 4;
    const int i0 = (bid & 15) << 6;
    const int r16 = l & 15;
    const int jo = (l >> 4) << 3;
    const int row = i0 + w * 16 + r16;

    const float s2m = s2maxg[b];
    const float s1v = s1g[b * NN + row];
    const float tt = s1v + s2m;
    const float Mr = fmaxf(tt, 0.1f * tt);

    const uint4* mrow = (const uint4*)(maskg + ((size_t)(b * NN) + row) * 128);
    const float* s2r = s2g + b * NN;
    const unsigned short* wb = whbt + (size_t)b * FOUT * NN + (size_t)r16 * NN;

    f32x4 acc[4];
    #pragma unroll
    for (int s = 0; s < 4; ++s)
        #pragma unroll
        for (int r = 0; r < 4; ++r) acc[s][r] = 0.f;
    float den = 0.f;

    for (int jt = 0; jt < NN; jt += 128) {
        uint4 mv = mrow[jt >> 7];
        const unsigned mw[4] = {mv.x, mv.y, mv.z, mv.w};
        #pragma unroll
        for (int c = 0; c < 4; ++c) {
            const int j0 = jt + c * 32 + jo;
            const unsigned m8 = (mw[c] >> jo) & 0xffu;
            float4 sa = *(const float4*)(s2r + j0);
            float4 sb = *(const float4*)(s2r + j0 + 4);
            short8 bfv[4];
            #pragma unroll
            for (int s = 0; s < 4; ++s)
                bfv[s] = *(const short8*)(wb + (size_t)s * (16 * NN) + j0);

            const float sv[8] = {sa.x, sa.y, sa.z, sa.w, sb.x, sb.y, sb.z, sb.w};
            unsigned pk[4];
            #pragma unroll
            for (int e = 0; e < 4; ++e) {
                float xa = s1v + sv[2*e];
                float xb = s1v + sv[2*e+1];
                float ea = fmaxf(xa, 0.1f * xa) - Mr;
                float eb = fmaxf(xb, 0.1f * xb) - Mr;
                float pa = (m8 >> (2*e))     & 1u ? __expf(ea) : 0.f;
                float pb = (m8 >> (2*e + 1)) & 1u ? __expf(eb) : 0.f;
                den += pa + pb;
                pk[e] = packbf(pa, pb);
            }
            union { unsigned u[4]; short8 s8; } A;
            A.u[0] = pk[0]; A.u[1] = pk[1]; A.u[2] = pk[2]; A.u[3] = pk[3];
            #pragma unroll
            for (int s = 0; s < 4; ++s)
                acc[s] = __builtin_amdgcn_mfma_f32_16x16x32_bf16(A.s8, bfv[s], acc[s], 0, 0, 0);
        }
    }

    den += __shfl_xor(den, 16, 64);
    den += __shfl_xor(den, 32, 64);

    const int rb = (l >> 4) << 2;
    float inv[4];
    #pragma unroll
    for (int rr = 0; rr < 4; ++rr) {
        float dd = __shfl(den, rb + rr, 64);
        inv[rr] = dd > 0.f ? 1.f / dd : 0.f;
    }
    float* orow = outg + ((size_t)(b * NN + i0 + w * 16 + rb)) * FOUT;
    #pragma unroll
    for (int s = 0; s < 4; ++s)
        #pragma unroll
        for (int rr = 0; rr < 4; ++rr) {
            float v = acc[s][rr] * inv[rr];
            float res = v > 0.f ? v : (__expf(v) - 1.f);
            orow[(size_t)rr * FOUT + s * 16 + r16] = res;
        }
}

extern "C" void kernel_launch(void* const* d_in, const int* in_sizes, int n_in,
                              void* d_out, int out_size, void* d_ws, size_t ws_size,
                              hipStream_t stream) {
    const float* atoms = (const float*)d_in[0];
    const int*   adj   = (const int*)d_in[1];
    const float* W     = (const float*)d_in[2];
    const float* a     = (const float*)d_in[3];
    float* out = (float*)d_out;

    char* ws = (char*)d_ws;
    unsigned short* whbt = (unsigned short*)ws;                  // 8 MB
    float* s1g    = (float*)(ws + (8u << 20));
    float* s2g    = (float*)(ws + (8u << 20) + (256u << 10));
    float* s2maxg = (float*)(ws + (8u << 20) + (512u << 10));
    unsigned char* mask = (unsigned char*)(ws + (9u << 20));     // 8 MB

    k1_proj<<<1024, 256, 0, stream>>>(atoms, W, a, whbt, s1g, s2g);
    k1b_max<<<64, 256, 0, stream>>>(s2g, s2maxg);
    k2a2_pack<<<8192, 256, 0, stream>>>((const i32x4*)adj, (unsigned*)mask);
    k2b_attn<<<1024, 256, 0, stream>>>(mask, whbt, s1g, s2g, s2maxg, out);
}

// Round 7
// 210.046 us; speedup vs baseline: 9.0565x; 1.0032x over previous
//
#include <hip/hip_runtime.h>
#include <hip/hip_bf16.h>

#define NN   1024
#define FIN  128
#define FOUT 64

typedef __attribute__((ext_vector_type(8))) short short8;
typedef __attribute__((ext_vector_type(4))) float f32x4;
typedef __attribute__((ext_vector_type(4))) int   i32x4;

__device__ inline unsigned short f2bf(float x) {
    union { __hip_bfloat16 h; unsigned short u; } c;
    c.h = __float2bfloat16(x);
    return c.u;
}
__device__ inline unsigned packbf(float a, float b) {
    return (unsigned)f2bf(a) | ((unsigned)f2bf(b) << 16);
}

// ---------------- Kernel 1: Wh = X @ W (fp32, LDS), s1/s2 scores, Wh^T bf16
__global__ __launch_bounds__(256) void k1_proj(
    const float* __restrict__ X, const float* __restrict__ W,
    const float* __restrict__ a,
    unsigned short* __restrict__ whbt,
    float* __restrict__ s1g, float* __restrict__ s2g)
{
    __shared__ float Ws[FIN][FOUT];
    __shared__ float Xs[64][FIN + 4];
    __shared__ unsigned short Ob[FOUT][64];

    const int t = threadIdx.x;
    const int blk = blockIdx.x;
    const int b = blk >> 4;
    const int r0 = (blk & 15) << 6;
    const float* Xg = X + ((size_t)(b * NN + r0)) * FIN;

    const float4* Wg4 = (const float4*)W;
    #pragma unroll
    for (int i = 0; i < 8; ++i) {
        int idx = t + i * 256;
        float4 v = Wg4[idx];
        int kk = idx >> 4, oo = (idx & 15) << 2;
        *(float4*)&Ws[kk][oo] = v;
    }
    #pragma unroll
    for (int i = 0; i < 8; ++i) {
        int idx = t + i * 256;
        float4 v = ((const float4*)Xg)[idx];
        int rr = idx >> 5, cc = (idx & 31) << 2;
        *(float4*)&Xs[rr][cc] = v;
    }
    __syncthreads();

    const int l = t & 63, w = t >> 6;
    const int c0 = (l & 15) << 2;
    const int rs = l >> 4;
    const int rbase = w * 16 + rs * 4;

    float acc[4][4] = {};
    for (int k = 0; k < FIN; ++k) {
        float4 wv = *(const float4*)&Ws[k][c0];
        #pragma unroll
        for (int q = 0; q < 4; ++q) {
            float x = Xs[rbase + q][k];
            acc[q][0] += x * wv.x; acc[q][1] += x * wv.y;
            acc[q][2] += x * wv.z; acc[q][3] += x * wv.w;
        }
    }

    float a1v[4], a2v[4];
    #pragma unroll
    for (int c = 0; c < 4; ++c) { a1v[c] = a[c0 + c]; a2v[c] = a[FOUT + c0 + c]; }
    #pragma unroll
    for (int q = 0; q < 4; ++q) {
        float p1 = acc[q][0]*a1v[0] + acc[q][1]*a1v[1] + acc[q][2]*a1v[2] + acc[q][3]*a1v[3];
        float p2 = acc[q][0]*a2v[0] + acc[q][1]*a2v[1] + acc[q][2]*a2v[2] + acc[q][3]*a2v[3];
        #pragma unroll
        for (int m = 1; m <= 8; m <<= 1) {
            p1 += __shfl_xor(p1, m, 64);
            p2 += __shfl_xor(p2, m, 64);
        }
        if ((l & 15) == 0) {
            int row = r0 + rbase + q;
            s1g[b * NN + row] = p1;
            s2g[b * NN + row] = p2;
        }
    }

    #pragma unroll
    for (int q = 0; q < 4; ++q)
        #pragma unroll
        for (int c = 0; c < 4; ++c)
            Ob[c0 + c][rbase + q] = f2bf(acc[q][c]);
    __syncthreads();

    {
        int o = t >> 2, rseg = (t & 3) << 4;
        unsigned short* dst = whbt + ((size_t)(b * FOUT + o)) * NN + r0 + rseg;
        const unsigned short* sp = &Ob[o][rseg];
        *(float4*)dst       = *(const float4*)sp;
        *(float4*)(dst + 8) = *(const float4*)(sp + 8);
    }
}

// ---------------- Kernel 1b: s2max per batch
__global__ __launch_bounds__(256) void k1b_max(
    const float* __restrict__ s2g, float* __restrict__ s2max)
{
    int b = blockIdx.x, t = threadIdx.x;
    float m = -3.4e38f;
    #pragma unroll
    for (int i = 0; i < 4; ++i) m = fmaxf(m, s2g[b * NN + t + i * 256]);
    #pragma unroll
    for (int d = 1; d <= 32; d <<= 1) m = fmaxf(m, __shfl_xor(m, d, 64));
    __shared__ float red[4];
    if ((t & 63) == 0) red[t >> 6] = m;
    __syncthreads();
    if (t == 0) s2max[b] = fmaxf(fmaxf(red[0], red[1]), fmaxf(red[2], red[3]));
}

// ---------------- k2a2: streaming pack, 1 thread = 32 ints -> 1 uint.
// Contiguous 128 B/thread, 8 KB/wave; 8 independent int4 loads before ALU.
// Bit j of mask32[tid] = adj[32*tid+j]&1. Adjacency stays L3-resident across
// timed replays (memory-side Infinity Cache) -> ~8-12 us warm.
__global__ __launch_bounds__(256) void k2a2_pack(
    const i32x4* __restrict__ adj4, unsigned* __restrict__ mask32)
{
    const size_t tid = (size_t)blockIdx.x * 256 + threadIdx.x;  // 2M threads
    const i32x4* p = adj4 + tid * 8;
    i32x4 v[8];
    #pragma unroll
    for (int i = 0; i < 8; ++i) v[i] = __builtin_nontemporal_load(p + i);
    unsigned m = 0;
    #pragma unroll
    for (int i = 0; i < 8; ++i) {
        m |= (unsigned)(v[i].x & 1) << (4 * i)
           | (unsigned)(v[i].y & 1) << (4 * i + 1)
           | (unsigned)(v[i].z & 1) << (4 * i + 2)
           | (unsigned)(v[i].w & 1) << (4 * i + 3);
    }
    mask32[tid] = m;
}

// ---------------- k2b: mask-driven fused attention (validated R4/R6 path)
__global__ __launch_bounds__(256) void k2b_attn(
    const unsigned char* __restrict__ maskg,
    const unsigned short* __restrict__ whbt,
    const float* __restrict__ s1g, const float* __restrict__ s2g,
    const float* __restrict__ s2maxg,
    float* __restrict__ outg)
{
    const int t = threadIdx.x, l = t & 63, w = t >> 6;
    const int bid = blockIdx.x;
    const int b = bid >> 4;
    const int i0 = (bid & 15) << 6;
    const int r16 = l & 15;
    const int jo = (l >> 4) << 3;
    const int row = i0 + w * 16 + r16;

    const float s2m = s2maxg[b];
    const float s1v = s1g[b * NN + row];
    const float tt = s1v + s2m;
    const float Mr = fmaxf(tt, 0.1f * tt);

    const uint4* mrow = (const uint4*)(maskg + ((size_t)(b * NN) + row) * 128);
    const float* s2r = s2g + b * NN;
    const unsigned short* wb = whbt + (size_t)b * FOUT * NN + (size_t)r16 * NN;

    f32x4 acc[4];
    #pragma unroll
    for (int s = 0; s < 4; ++s)
        #pragma unroll
        for (int r = 0; r < 4; ++r) acc[s][r] = 0.f;
    float den = 0.f;

    for (int jt = 0; jt < NN; jt += 128) {
        uint4 mv = mrow[jt >> 7];
        const unsigned mw[4] = {mv.x, mv.y, mv.z, mv.w};
        #pragma unroll
        for (int c = 0; c < 4; ++c) {
            const int j0 = jt + c * 32 + jo;
            const unsigned m8 = (mw[c] >> jo) & 0xffu;
            float4 sa = *(const float4*)(s2r + j0);
            float4 sb = *(const float4*)(s2r + j0 + 4);
            short8 bfv[4];
            #pragma unroll
            for (int s = 0; s < 4; ++s)
                bfv[s] = *(const short8*)(wb + (size_t)s * (16 * NN) + j0);

            const float sv[8] = {sa.x, sa.y, sa.z, sa.w, sb.x, sb.y, sb.z, sb.w};
            unsigned pk[4];
            #pragma unroll
            for (int e = 0; e < 4; ++e) {
                float xa = s1v + sv[2*e];
                float xb = s1v + sv[2*e+1];
                float ea = fmaxf(xa, 0.1f * xa) - Mr;
                float eb = fmaxf(xb, 0.1f * xb) - Mr;
                float pa = (m8 >> (2*e))     & 1u ? __expf(ea) : 0.f;
                float pb = (m8 >> (2*e + 1)) & 1u ? __expf(eb) : 0.f;
                den += pa + pb;
                pk[e] = packbf(pa, pb);
            }
            union { unsigned u[4]; short8 s8; } A;
            A.u[0] = pk[0]; A.u[1] = pk[1]; A.u[2] = pk[2]; A.u[3] = pk[3];
            #pragma unroll
            for (int s = 0; s < 4; ++s)
                acc[s] = __builtin_amdgcn_mfma_f32_16x16x32_bf16(A.s8, bfv[s], acc[s], 0, 0, 0);
        }
    }

    den += __shfl_xor(den, 16, 64);
    den += __shfl_xor(den, 32, 64);

    const int rb = (l >> 4) << 2;
    float inv[4];
    #pragma unroll
    for (int rr = 0; rr < 4; ++rr) {
        float dd = __shfl(den, rb + rr, 64);
        inv[rr] = dd > 0.f ? 1.f / dd : 0.f;
    }
    float* orow = outg + ((size_t)(b * NN + i0 + w * 16 + rb)) * FOUT;
    #pragma unroll
    for (int s = 0; s < 4; ++s)
        #pragma unroll
        for (int rr = 0; rr < 4; ++rr) {
            float v = acc[s][rr] * inv[rr];
            float res = v > 0.f ? v : (__expf(v) - 1.f);
            orow[(size_t)rr * FOUT + s * 16 + r16] = res;
        }
}

extern "C" void kernel_launch(void* const* d_in, const int* in_sizes, int n_in,
                              void* d_out, int out_size, void* d_ws, size_t ws_size,
                              hipStream_t stream) {
    const float* atoms = (const float*)d_in[0];
    const int*   adj   = (const int*)d_in[1];
    const float* W     = (const float*)d_in[2];
    const float* a     = (const float*)d_in[3];
    float* out = (float*)d_out;

    char* ws = (char*)d_ws;
    unsigned short* whbt = (unsigned short*)ws;                  // 8 MB
    float* s1g    = (float*)(ws + (8u << 20));
    float* s2g    = (float*)(ws + (8u << 20) + (256u << 10));
    float* s2maxg = (float*)(ws + (8u << 20) + (512u << 10));
    unsigned char* mask = (unsigned char*)(ws + (9u << 20));     // 8 MB

    k1_proj<<<1024, 256, 0, stream>>>(atoms, W, a, whbt, s1g, s2g);
    k1b_max<<<64, 256, 0, stream>>>(s2g, s2maxg);
    k2a2_pack<<<8192, 256, 0, stream>>>((const i32x4*)adj, (unsigned*)mask);
    k2b_attn<<<1024, 256, 0, stream>>>(mask, whbt, s1g, s2g, s2maxg, out);
}

// Round 8
// 149.398 us; speedup vs baseline: 12.7330x; 1.4060x over previous
//
#include <hip/hip_runtime.h>
#include <hip/hip_bf16.h>

#define NN   1024
#define FIN  128
#define FOUT 64

typedef __attribute__((ext_vector_type(8))) short short8;
typedef __attribute__((ext_vector_type(4))) float f32x4;
typedef __attribute__((ext_vector_type(4))) int   i32x4;

__device__ inline unsigned short f2bf(float x) {
    union { __hip_bfloat16 h; unsigned short u; } c;
    c.h = __float2bfloat16(x);
    return c.u;
}
__device__ inline unsigned packbf(float a, float b) {
    return (unsigned)f2bf(a) | ((unsigned)f2bf(b) << 16);
}

// ---------------- Kernel 1: Wh = X @ W (fp32, LDS), s1/s2 scores, Wh^T bf16
__global__ __launch_bounds__(256) void k1_proj(
    const float* __restrict__ X, const float* __restrict__ W,
    const float* __restrict__ a,
    unsigned short* __restrict__ whbt,
    float* __restrict__ s1g, float* __restrict__ s2g)
{
    __shared__ float Ws[FIN][FOUT];
    __shared__ float Xs[64][FIN + 4];
    __shared__ unsigned short Ob[FOUT][64];

    const int t = threadIdx.x;
    const int blk = blockIdx.x;
    const int b = blk >> 4;
    const int r0 = (blk & 15) << 6;
    const float* Xg = X + ((size_t)(b * NN + r0)) * FIN;

    const float4* Wg4 = (const float4*)W;
    #pragma unroll
    for (int i = 0; i < 8; ++i) {
        int idx = t + i * 256;
        float4 v = Wg4[idx];
        int kk = idx >> 4, oo = (idx & 15) << 2;
        *(float4*)&Ws[kk][oo] = v;
    }
    #pragma unroll
    for (int i = 0; i < 8; ++i) {
        int idx = t + i * 256;
        float4 v = ((const float4*)Xg)[idx];
        int rr = idx >> 5, cc = (idx & 31) << 2;
        *(float4*)&Xs[rr][cc] = v;
    }
    __syncthreads();

    const int l = t & 63, w = t >> 6;
    const int c0 = (l & 15) << 2;
    const int rs = l >> 4;
    const int rbase = w * 16 + rs * 4;

    float acc[4][4] = {};
    for (int k = 0; k < FIN; ++k) {
        float4 wv = *(const float4*)&Ws[k][c0];
        #pragma unroll
        for (int q = 0; q < 4; ++q) {
            float x = Xs[rbase + q][k];
            acc[q][0] += x * wv.x; acc[q][1] += x * wv.y;
            acc[q][2] += x * wv.z; acc[q][3] += x * wv.w;
        }
    }

    float a1v[4], a2v[4];
    #pragma unroll
    for (int c = 0; c < 4; ++c) { a1v[c] = a[c0 + c]; a2v[c] = a[FOUT + c0 + c]; }
    #pragma unroll
    for (int q = 0; q < 4; ++q) {
        float p1 = acc[q][0]*a1v[0] + acc[q][1]*a1v[1] + acc[q][2]*a1v[2] + acc[q][3]*a1v[3];
        float p2 = acc[q][0]*a2v[0] + acc[q][1]*a2v[1] + acc[q][2]*a2v[2] + acc[q][3]*a2v[3];
        #pragma unroll
        for (int m = 1; m <= 8; m <<= 1) {
            p1 += __shfl_xor(p1, m, 64);
            p2 += __shfl_xor(p2, m, 64);
        }
        if ((l & 15) == 0) {
            int row = r0 + rbase + q;
            s1g[b * NN + row] = p1;
            s2g[b * NN + row] = p2;
        }
    }

    #pragma unroll
    for (int q = 0; q < 4; ++q)
        #pragma unroll
        for (int c = 0; c < 4; ++c)
            Ob[c0 + c][rbase + q] = f2bf(acc[q][c]);
    __syncthreads();

    {
        int o = t >> 2, rseg = (t & 3) << 4;
        unsigned short* dst = whbt + ((size_t)(b * FOUT + o)) * NN + r0 + rseg;
        const unsigned short* sp = &Ob[o][rseg];
        *(float4*)dst       = *(const float4*)sp;
        *(float4*)(dst + 8) = *(const float4*)(sp + 8);
    }
}

// ---------------- Kernel 1b: s2max per batch
__global__ __launch_bounds__(256) void k1b_max(
    const float* __restrict__ s2g, float* __restrict__ s2max)
{
    int b = blockIdx.x, t = threadIdx.x;
    float m = -3.4e38f;
    #pragma unroll
    for (int i = 0; i < 4; ++i) m = fmaxf(m, s2g[b * NN + t + i * 256]);
    #pragma unroll
    for (int d = 1; d <= 32; d <<= 1) m = fmaxf(m, __shfl_xor(m, d, 64));
    __shared__ float red[4];
    if ((t & 63) == 0) red[t >> 6] = m;
    __syncthreads();
    if (t == 0) s2max[b] = fmaxf(fmaxf(red[0], red[1]), fmaxf(red[2], red[3]));
}

// ---------------- k2a3: streaming pack, PLAIN loads (cacheable).
// 1 thread = 32 contiguous ints (128 B) -> 1 uint. 8 int4 loads issued
// back-to-back before any ALU; wave reads 8 KB contiguous, stores 256 B.
// Little-endian uint32 layout == byte layout k2b consumes.
__global__ __launch_bounds__(256) void k2a3_pack(
    const i32x4* __restrict__ adj4, unsigned* __restrict__ mask32)
{
    const size_t tid = (size_t)blockIdx.x * 256 + threadIdx.x;  // 2M threads
    const i32x4* p = adj4 + tid * 8;
    i32x4 v[8];
    #pragma unroll
    for (int i = 0; i < 8; ++i) v[i] = p[i];
    unsigned m = 0;
    #pragma unroll
    for (int i = 0; i < 8; ++i) {
        m |= (unsigned)(v[i].x & 1) << (4 * i)
           | (unsigned)(v[i].y & 1) << (4 * i + 1)
           | (unsigned)(v[i].z & 1) << (4 * i + 2)
           | (unsigned)(v[i].w & 1) << (4 * i + 3);
    }
    mask32[tid] = m;
}

// ---------------- k2b: mask-driven fused attention (validated R4/R6/R7 path)
__global__ __launch_bounds__(256) void k2b_attn(
    const unsigned char* __restrict__ maskg,
    const unsigned short* __restrict__ whbt,
    const float* __restrict__ s1g, const float* __restrict__ s2g,
    const float* __restrict__ s2maxg,
    float* __restrict__ outg)
{
    const int t = threadIdx.x, l = t & 63, w = t >> 6;
    const int bid = blockIdx.x;
    const int b = bid >> 4;
    const int i0 = (bid & 15) << 6;
    const int r16 = l & 15;
    const int jo = (l >> 4) << 3;
    const int row = i0 + w * 16 + r16;

    const float s2m = s2maxg[b];
    const float s1v = s1g[b * NN + row];
    const float tt = s1v + s2m;
    const float Mr = fmaxf(tt, 0.1f * tt);

    const uint4* mrow = (const uint4*)(maskg + ((size_t)(b * NN) + row) * 128);
    const float* s2r = s2g + b * NN;
    const unsigned short* wb = whbt + (size_t)b * FOUT * NN + (size_t)r16 * NN;

    f32x4 acc[4];
    #pragma unroll
    for (int s = 0; s < 4; ++s)
        #pragma unroll
        for (int r = 0; r < 4; ++r) acc[s][r] = 0.f;
    float den = 0.f;

    for (int jt = 0; jt < NN; jt += 128) {
        uint4 mv = mrow[jt >> 7];
        const unsigned mw[4] = {mv.x, mv.y, mv.z, mv.w};
        #pragma unroll
        for (int c = 0; c < 4; ++c) {
            const int j0 = jt + c * 32 + jo;
            const unsigned m8 = (mw[c] >> jo) & 0xffu;
            float4 sa = *(const float4*)(s2r + j0);
            float4 sb = *(const float4*)(s2r + j0 + 4);
            short8 bfv[4];
            #pragma unroll
            for (int s = 0; s < 4; ++s)
                bfv[s] = *(const short8*)(wb + (size_t)s * (16 * NN) + j0);

            const float sv[8] = {sa.x, sa.y, sa.z, sa.w, sb.x, sb.y, sb.z, sb.w};
            unsigned pk[4];
            #pragma unroll
            for (int e = 0; e < 4; ++e) {
                float xa = s1v + sv[2*e];
                float xb = s1v + sv[2*e+1];
                float ea = fmaxf(xa, 0.1f * xa) - Mr;
                float eb = fmaxf(xb, 0.1f * xb) - Mr;
                float pa = (m8 >> (2*e))     & 1u ? __expf(ea) : 0.f;
                float pb = (m8 >> (2*e + 1)) & 1u ? __expf(eb) : 0.f;
                den += pa + pb;
                pk[e] = packbf(pa, pb);
            }
            union { unsigned u[4]; short8 s8; } A;
            A.u[0] = pk[0]; A.u[1] = pk[1]; A.u[2] = pk[2]; A.u[3] = pk[3];
            #pragma unroll
            for (int s = 0; s < 4; ++s)
                acc[s] = __builtin_amdgcn_mfma_f32_16x16x32_bf16(A.s8, bfv[s], acc[s], 0, 0, 0);
        }
    }

    den += __shfl_xor(den, 16, 64);
    den += __shfl_xor(den, 32, 64);

    const int rb = (l >> 4) << 2;
    float inv[4];
    #pragma unroll
    for (int rr = 0; rr < 4; ++rr) {
        float dd = __shfl(den, rb + rr, 64);
        inv[rr] = dd > 0.f ? 1.f / dd : 0.f;
    }
    float* orow = outg + ((size_t)(b * NN + i0 + w * 16 + rb)) * FOUT;
    #pragma unroll
    for (int s = 0; s < 4; ++s)
        #pragma unroll
        for (int rr = 0; rr < 4; ++rr) {
            float v = acc[s][rr] * inv[rr];
            float res = v > 0.f ? v : (__expf(v) - 1.f);
            orow[(size_t)rr * FOUT + s * 16 + r16] = res;
        }
}

extern "C" void kernel_launch(void* const* d_in, const int* in_sizes, int n_in,
                              void* d_out, int out_size, void* d_ws, size_t ws_size,
                              hipStream_t stream) {
    const float* atoms = (const float*)d_in[0];
    const int*   adj   = (const int*)d_in[1];
    const float* W     = (const float*)d_in[2];
    const float* a     = (const float*)d_in[3];
    float* out = (float*)d_out;

    char* ws = (char*)d_ws;
    unsigned short* whbt = (unsigned short*)ws;                  // 8 MB
    float* s1g    = (float*)(ws + (8u << 20));
    float* s2g    = (float*)(ws + (8u << 20) + (256u << 10));
    float* s2maxg = (float*)(ws + (8u << 20) + (512u << 10));
    unsigned char* mask = (unsigned char*)(ws + (9u << 20));     // 8 MB

    k1_proj<<<1024, 256, 0, stream>>>(atoms, W, a, whbt, s1g, s2g);
    k1b_max<<<64, 256, 0, stream>>>(s2g, s2maxg);
    k2a3_pack<<<8192, 256, 0, stream>>>((const i32x4*)adj, (unsigned*)mask);
    k2b_attn<<<1024, 256, 0, stream>>>(mask, whbt, s1g, s2g, s2maxg, out);
}